// Round 4
// baseline (1826.844 us; speedup 1.0000x reference)
//
#include <hip/hip_runtime.h>
#include <hip/hip_bf16.h>
#include <stdint.h>

typedef __attribute__((ext_vector_type(8))) short bf16x8;   // 8 bf16 = 4 VGPRs
typedef __attribute__((ext_vector_type(4))) float f32x4;
typedef __hip_bfloat16 bf16;

static constexpr long NTOK = 16384;  // B*S
static constexpr long DD   = 1024;
static constexpr long HH   = 2048;

// ---------- small helpers ----------
__device__ __forceinline__ float bf2f(unsigned short u) {
  union { unsigned int i; float f; } v; v.i = ((unsigned int)u) << 16; return v.f;
}
__device__ __forceinline__ unsigned short f2bfu(float f) {
  __hip_bfloat16 h = __float2bfloat16(f);
  union { __hip_bfloat16 h; unsigned short u; } v; v.h = h; return v.u;
}

// ---------- elementwise converts ----------
__global__ void cvt4_kernel(const float* __restrict__ src, bf16* __restrict__ dst, long n) {
  long i = ((long)blockIdx.x * blockDim.x + threadIdx.x) * 4;
  long stride = (long)gridDim.x * blockDim.x * 4;
  for (; i < n; i += stride) {
    float4 f = *reinterpret_cast<const float4*>(src + i);
    ushort4 u;
    u.x = f2bfu(f.x); u.y = f2bfu(f.y); u.z = f2bfu(f.z); u.w = f2bfu(f.w);
    *reinterpret_cast<ushort4*>(dst + i) = u;
  }
}

// fp32 [R][C] -> bf16 [C][R]
__global__ void cvtT_kernel(const float* __restrict__ src, bf16* __restrict__ dst, int R, int C) {
  __shared__ float t[64][65];
  int tx = threadIdx.x, ty = threadIdx.y;
  long r0 = (long)blockIdx.y * 64, c0 = (long)blockIdx.x * 64;
#pragma unroll
  for (int i = 0; i < 4; ++i) t[ty * 4 + i][tx] = src[(r0 + ty * 4 + i) * C + c0 + tx];
  __syncthreads();
#pragma unroll
  for (int i = 0; i < 4; ++i)
    dst[(c0 + ty * 4 + i) * R + r0 + tx] = __float2bfloat16(t[tx][ty * 4 + i]);
}

// bf16 [R][C] -> bf16 [C][R]
__global__ void tr_bf16_kernel(const bf16* __restrict__ src, bf16* __restrict__ dst, int R, int C) {
  __shared__ bf16 t[64][65];
  int tx = threadIdx.x, ty = threadIdx.y;
  long r0 = (long)blockIdx.y * 64, c0 = (long)blockIdx.x * 64;
#pragma unroll
  for (int i = 0; i < 4; ++i) t[ty * 4 + i][tx] = src[(r0 + ty * 4 + i) * C + c0 + tx];
  __syncthreads();
#pragma unroll
  for (int i = 0; i < 4; ++i)
    dst[(c0 + ty * 4 + i) * R + r0 + tx] = t[tx][ty * 4 + i];
}

// bf16 [R][C] -> silu(.) -> bf16 [C][R]
__global__ void tr_silu_kernel(const bf16* __restrict__ src, bf16* __restrict__ dst, int R, int C) {
  __shared__ bf16 t[64][65];
  int tx = threadIdx.x, ty = threadIdx.y;
  long r0 = (long)blockIdx.y * 64, c0 = (long)blockIdx.x * 64;
#pragma unroll
  for (int i = 0; i < 4; ++i) {
    float zv = __bfloat162float(src[(r0 + ty * 4 + i) * C + c0 + tx]);
    t[ty * 4 + i][tx] = __float2bfloat16(zv / (1.f + __expf(-zv)));
  }
  __syncthreads();
#pragma unroll
  for (int i = 0; i < 4; ++i)
    dst[(c0 + ty * 4 + i) * R + r0 + tx] = t[tx][ty * 4 + i];
}

// M1n = (1-alpha)*M1 + eta*S1 - theta*g1  (and M2 likewise), write bf16
__global__ void update_kernel(const float* __restrict__ M1, const float* __restrict__ M2,
                              const float* __restrict__ S1, const float* __restrict__ S2,
                              const float* __restrict__ g1, const float* __restrict__ g2,
                              const float* __restrict__ sums,
                              bf16* __restrict__ M1nb, bf16* __restrict__ M2nb) {
  const float inv = 1.f / (float)(NTOK * DD);
  const float alpha = sums[0] * inv, theta = sums[1] * inv, eta = sums[2] * inv;
  const long n = HH * DD;
  long i = (long)blockIdx.x * blockDim.x + threadIdx.x;
  long stride = (long)gridDim.x * blockDim.x;
  for (; i < 2 * n; i += stride) {
    if (i < n) {
      float mn = (1.f - alpha) * M1[i] + (eta * S1[i] - theta * g1[i]);
      M1nb[i] = __float2bfloat16(mn);
    } else {
      long j = i - n;
      float mn = (1.f - alpha) * M2[j] + (eta * S2[j] - theta * g2[j]);
      M2nb[j] = __float2bfloat16(mn);
    }
  }
}

// ---------- NT GEMM: C[NROW x MCOL] = A[NROW x K] * B[MCOL x K]^T ----------
// m97 structure: 128x128 tile, BK=32, 4 waves each 64x64 (4x4 of 16x16x32 MFMA).
__device__ __forceinline__ void gload16(const bf16* g, bf16* l) {
  __builtin_amdgcn_global_load_lds(
      (__attribute__((address_space(1))) const unsigned int*)g,
      (__attribute__((address_space(3))) unsigned int*)l,
      16, 0, 0);
}

// EPI: 0=store bf16, 1=store f32, 2=atomicAdd f32 (split-K), 3=sigmoid-sum scalar,
//      4=silu->bf16, 6=escale*(acc - vaux)->bf16, 7=acc*silu'(vaux as z)->bf16
// ASILU: stage A as silu(A) via registers (A never materialized with silu applied)
template <int EPI, int ASILU>
__global__ __launch_bounds__(256)
void gemm_nt_kernel(const bf16* __restrict__ A, const bf16* __restrict__ B,
                    bf16* __restrict__ Cbf, float* __restrict__ Cf,
                    float* __restrict__ scalar_out,
                    const float* __restrict__ bias, const bf16* __restrict__ vaux,
                    float escale, int MCOL, long K, int ksteps) {
  __shared__ __align__(16) bf16 As[128 * 32];
  __shared__ __align__(16) bf16 Bs[128 * 32];
  const int tid = threadIdx.x;
  const int lane = tid & 63;
  const int wave = tid >> 6;
  const int wr = wave >> 1, wc = wave & 1;
  const long row0 = (long)blockIdx.y * 128;
  const long col0 = (long)blockIdx.x * 128;
  const long kbase = (long)blockIdx.z * (long)ksteps * 32;

  const int srow = tid >> 2;            // 0..63
  const int scol = (tid & 3) * 8;       // 0,8,16,24
  const bf16* Ag = A + (row0 + srow) * K + kbase + scol;
  const bf16* Bg = B + (col0 + srow) * K + kbase + scol;
  bf16* Asl0 = As + tid * 8;
  bf16* Asl1 = As + 2048 + tid * 8;
  bf16* Bsl0 = Bs + tid * 8;
  bf16* Bsl1 = Bs + 2048 + tid * 8;

  f32x4 acc[4][4];
#pragma unroll
  for (int m = 0; m < 4; ++m)
#pragma unroll
    for (int n = 0; n < 4; ++n)
      acc[m][n] = (f32x4){0.f, 0.f, 0.f, 0.f};

  const int aoff = (wr * 64 + (lane & 15)) * 32 + (lane >> 4) * 8;
  const int boff = (wc * 64 + (lane & 15)) * 32 + (lane >> 4) * 8;

  for (int kt = 0; kt < ksteps; ++kt) {
    const long ko = (long)kt * 32;
    if constexpr (ASILU) {
      bf16x8 a0 = *reinterpret_cast<const bf16x8*>(Ag + ko);
      bf16x8 a1 = *reinterpret_cast<const bf16x8*>(Ag + 64 * K + ko);
      bf16x8 s0, s1;
#pragma unroll
      for (int j = 0; j < 8; ++j) {
        float z0 = bf2f((unsigned short)a0[j]);
        float z1 = bf2f((unsigned short)a1[j]);
        s0[j] = (short)f2bfu(z0 / (1.f + __expf(-z0)));
        s1[j] = (short)f2bfu(z1 / (1.f + __expf(-z1)));
      }
      *reinterpret_cast<bf16x8*>(Asl0) = s0;
      *reinterpret_cast<bf16x8*>(Asl1) = s1;
    } else {
      gload16(Ag + ko, Asl0);
      gload16(Ag + 64 * K + ko, Asl1);
    }
    gload16(Bg + ko, Bsl0);
    gload16(Bg + 64 * K + ko, Bsl1);
    __syncthreads();
    bf16x8 af[4], bv[4];
#pragma unroll
    for (int m = 0; m < 4; ++m)
      af[m] = *reinterpret_cast<const bf16x8*>(As + aoff + m * 16 * 32);
#pragma unroll
    for (int n = 0; n < 4; ++n)
      bv[n] = *reinterpret_cast<const bf16x8*>(Bs + boff + n * 16 * 32);
#pragma unroll
    for (int m = 0; m < 4; ++m)
#pragma unroll
      for (int n = 0; n < 4; ++n)
        acc[m][n] = __builtin_amdgcn_mfma_f32_16x16x32_bf16(af[m], bv[n], acc[m][n], 0, 0, 0);
    __syncthreads();
  }

  float lsum = 0.f;
#pragma unroll
  for (int m = 0; m < 4; ++m) {
#pragma unroll
    for (int n = 0; n < 4; ++n) {
      const long col = col0 + wc * 64 + n * 16 + (lane & 15);
#pragma unroll
      for (int r = 0; r < 4; ++r) {
        const long row = row0 + wr * 64 + m * 16 + (lane >> 4) * 4 + r;
        const long idx = row * MCOL + col;
        float val = acc[m][n][r];
        if constexpr (EPI == 0) {
          Cbf[idx] = __float2bfloat16(val);
        } else if constexpr (EPI == 1) {
          Cf[idx] = val;
        } else if constexpr (EPI == 2) {
          atomicAdd(&Cf[idx], val);
        } else if constexpr (EPI == 3) {
          lsum += 1.f / (1.f + __expf(-(val + bias[col])));
        } else if constexpr (EPI == 4) {
          Cbf[idx] = __float2bfloat16(val / (1.f + __expf(-val)));
        } else if constexpr (EPI == 6) {
          Cbf[idx] = __float2bfloat16(escale * (val - __bfloat162float(vaux[idx])));
        } else if constexpr (EPI == 7) {
          float zv = __bfloat162float(vaux[idx]);
          float s = 1.f / (1.f + __expf(-zv));
          Cbf[idx] = __float2bfloat16(val * (s * (1.f + zv * (1.f - s))));
        }
      }
    }
  }
  if constexpr (EPI == 3) {
#pragma unroll
    for (int off = 32; off > 0; off >>= 1) lsum += __shfl_down(lsum, off);
    float* red = reinterpret_cast<float*>(As);
    if (lane == 0) red[wave] = lsum;
    __syncthreads();
    if (tid == 0) atomicAdd(scalar_out, red[0] + red[1] + red[2] + red[3]);
  }
}

// ---------- host ----------
extern "C" void kernel_launch(void* const* d_in, const int* in_sizes, int n_in,
                              void* d_out, int out_size, void* d_ws, size_t ws_size,
                              hipStream_t stream) {
  (void)in_sizes; (void)n_in; (void)out_size;
  const float* x    = (const float*)d_in[0];
  const float* Wk   = (const float*)d_in[1];
  const float* Wv   = (const float*)d_in[2];
  const float* Wq   = (const float*)d_in[3];
  const float* Wout = (const float*)d_in[4];
  const float* Wgd  = (const float*)d_in[5];
  const float* bgd  = (const float*)d_in[6];
  const float* Wgl  = (const float*)d_in[7];
  const float* bgl  = (const float*)d_in[8];
  const float* Wgm  = (const float*)d_in[9];
  const float* bgm  = (const float*)d_in[10];
  const float* M1   = (const float*)d_in[11];
  const float* M2   = (const float*)d_in[12];
  const float* S1   = (const float*)d_in[13];
  const float* S2   = (const float*)d_in[14];

  char* p = (char*)d_ws;
  auto alloc = [&](size_t bytes) -> char* {
    char* r = p; p += (bytes + 255) & ~(size_t)255; return r;
  };
  // persistent (~50 MB)
  bf16* Wkb   = (bf16*)alloc(DD * DD * 2);
  bf16* Wvb   = (bf16*)alloc(DD * DD * 2);
  bf16* Wqb   = (bf16*)alloc(DD * DD * 2);
  bf16* Woutb = (bf16*)alloc(DD * DD * 2);
  bf16* Wgdb  = (bf16*)alloc(DD * DD * 2);
  bf16* Wglb  = (bf16*)alloc(DD * DD * 2);
  bf16* Wgmb  = (bf16*)alloc(DD * DD * 2);
  bf16* M1b   = (bf16*)alloc(HH * DD * 2);
  bf16* M2b   = (bf16*)alloc(HH * DD * 2);
  bf16* M2Tb  = (bf16*)alloc(HH * DD * 2);
  bf16* M1nb  = (bf16*)alloc(HH * DD * 2);
  bf16* M2nb  = (bf16*)alloc(HH * DD * 2);
  float* g1   = (float*)alloc(HH * DD * 4);
  float* g2   = (float*)alloc(HH * DD * 4);
  float* sums = (float*)alloc(256);
  const size_t persist = (size_t)(p - (char*)d_ws);

  // adaptive chunk size: footprint = persist + 20480*C (+ alignment slack)
  long C = NTOK;
  while (C > 512 && persist + (size_t)20480 * C + 4096 > ws_size) C >>= 1;
  if (persist + (size_t)20480 * C + 4096 > ws_size) return;  // hopeless: ws < ~61 MB
  const long NC = NTOK / C;

  // chunk slots (reused across chunks)
  bf16* cA = (bf16*)alloc(C * DD * 2);  // xb -> ret(aux)
  bf16* cB = (bf16*)alloc(C * DD * 2);  // k  -> dpredT / q (phase B)
  bf16* cC = (bf16*)alloc(C * DD * 2);  // v  -> kT
  bf16* cE = (bf16*)alloc(C * DD * 2);  // dpred -> ret (phase B)
  bf16* cD = (bf16*)alloc(C * HH * 2);  // z  -> r (phase B)
  bf16* cH = (bf16*)alloc(C * HH * 2);  // hT
  bf16* cI = (bf16*)alloc(C * HH * 2);  // dzT
  float* outf = (float*)d_out;

  (void)hipMemsetAsync(g1, 0, HH * DD * 4, stream);
  (void)hipMemsetAsync(g2, 0, HH * DD * 4, stream);
  (void)hipMemsetAsync(sums, 0, 256, stream);

  const dim3 b256(256);
  const dim3 tb(64, 16);

  // one-time setup conversions
  cvt4_kernel<<<512, b256, 0, stream>>>(Wk, Wkb, DD * DD);
  cvt4_kernel<<<512, b256, 0, stream>>>(Wv, Wvb, DD * DD);
  cvt4_kernel<<<512, b256, 0, stream>>>(Wq, Wqb, DD * DD);
  cvt4_kernel<<<512, b256, 0, stream>>>(Wout, Woutb, DD * DD);
  cvt4_kernel<<<512, b256, 0, stream>>>(Wgd, Wgdb, DD * DD);
  cvt4_kernel<<<512, b256, 0, stream>>>(Wgl, Wglb, DD * DD);
  cvt4_kernel<<<512, b256, 0, stream>>>(Wgm, Wgmb, DD * DD);
  cvt4_kernel<<<512, b256, 0, stream>>>(M1, M1b, HH * DD);
  cvt4_kernel<<<512, b256, 0, stream>>>(M2, M2b, HH * DD);
  cvtT_kernel<<<dim3(HH / 64, DD / 64), tb, 0, stream>>>(M2, M2Tb, (int)DD, (int)HH);

  const int splits = (int)(C >= 2048 ? C / 2048 : 1);
  const int kstG = (int)(C / (32L * splits));

  // ---------- phase A: forward + grads, per chunk ----------
  for (long c = 0; c < NC; ++c) {
    const float* xc = x + c * C * DD;
    bf16* dzc = (bf16*)d_out + c * C * HH;  // dz lives in d_out (dead before phase B)
    cvt4_kernel<<<2048, b256, 0, stream>>>(xc, cA, C * DD);
    // gates (accumulate sigmoid sums)
    gemm_nt_kernel<3, 0><<<dim3(DD/128, C/128, 1), b256, 0, stream>>>(cA, Wgdb, nullptr, nullptr, sums + 0, bgd, nullptr, 0.f, (int)DD, DD, 32);
    gemm_nt_kernel<3, 0><<<dim3(DD/128, C/128, 1), b256, 0, stream>>>(cA, Wglb, nullptr, nullptr, sums + 1, bgl, nullptr, 0.f, (int)DD, DD, 32);
    gemm_nt_kernel<3, 0><<<dim3(DD/128, C/128, 1), b256, 0, stream>>>(cA, Wgmb, nullptr, nullptr, sums + 2, bgm, nullptr, 0.f, (int)DD, DD, 32);
    // k, v
    gemm_nt_kernel<0, 0><<<dim3(DD/128, C/128, 1), b256, 0, stream>>>(cA, Wkb, cB, nullptr, nullptr, nullptr, nullptr, 0.f, (int)DD, DD, 32);
    gemm_nt_kernel<0, 0><<<dim3(DD/128, C/128, 1), b256, 0, stream>>>(cA, Wvb, cC, nullptr, nullptr, nullptr, nullptr, 0.f, (int)DD, DD, 32);
    // z = k@M1.T
    gemm_nt_kernel<0, 0><<<dim3(HH/128, C/128, 1), b256, 0, stream>>>(cB, M1b, cD, nullptr, nullptr, nullptr, nullptr, 0.f, (int)HH, DD, 32);
    // dpred = (2/D)*(silu(z)@M2.T - v)   [A silu-staged from z]
    gemm_nt_kernel<6, 1><<<dim3(DD/128, C/128, 1), b256, 0, stream>>>(cD, M2b, cE, nullptr, nullptr, nullptr, cC, 2.f / 1024.f, (int)DD, HH, 64);
    // dz = (dpred@M2) * silu'(z)  -> d_out region
    gemm_nt_kernel<7, 0><<<dim3(HH/128, C/128, 1), b256, 0, stream>>>(cE, M2Tb, dzc, nullptr, nullptr, nullptr, cD, 0.f, (int)HH, DD, 32);
    // transposes (v dead -> cC; k dead -> cB)
    tr_bf16_kernel<<<dim3(DD/64, C/64), tb, 0, stream>>>(cB, cC, (int)C, (int)DD);       // kT
    tr_bf16_kernel<<<dim3(DD/64, C/64), tb, 0, stream>>>(cE, cB, (int)C, (int)DD);       // dpredT
    tr_silu_kernel<<<dim3(HH/64, C/64), tb, 0, stream>>>(cD, cH, (int)C, (int)HH);       // hT = silu(z)^T
    tr_bf16_kernel<<<dim3(HH/64, C/64), tb, 0, stream>>>(dzc, cI, (int)C, (int)HH);      // dzT
    // g2[D,H] += dpred^T @ h ; g1[H,D] += dz^T @ k   (split-K atomics)
    gemm_nt_kernel<2, 0><<<dim3(HH/128, DD/128, splits), b256, 0, stream>>>(cB, cH, nullptr, g2, nullptr, nullptr, nullptr, 0.f, (int)HH, C, kstG);
    gemm_nt_kernel<2, 0><<<dim3(DD/128, HH/128, splits), b256, 0, stream>>>(cI, cC, nullptr, g1, nullptr, nullptr, nullptr, 0.f, (int)DD, C, kstG);
  }

  // ---------- update ----------
  update_kernel<<<4096, b256, 0, stream>>>(M1, M2, S1, S2, g1, g2, sums, M1nb, M2nb);

  // ---------- phase B: retrieve, per chunk ----------
  for (long c = 0; c < NC; ++c) {
    const float* xc = x + c * C * DD;
    cvt4_kernel<<<2048, b256, 0, stream>>>(xc, cA, C * DD);
    // q = x@Wq.T
    gemm_nt_kernel<0, 0><<<dim3(DD/128, C/128, 1), b256, 0, stream>>>(cA, Wqb, cB, nullptr, nullptr, nullptr, nullptr, 0.f, (int)DD, DD, 32);
    // r = silu(q@M1n.T)
    gemm_nt_kernel<4, 0><<<dim3(HH/128, C/128, 1), b256, 0, stream>>>(cB, M1nb, cD, nullptr, nullptr, nullptr, nullptr, 0.f, (int)HH, DD, 32);
    // ret = r@M2n.T
    gemm_nt_kernel<0, 0><<<dim3(DD/128, C/128, 1), b256, 0, stream>>>(cD, M2nb, cE, nullptr, nullptr, nullptr, nullptr, 0.f, (int)DD, HH, 64);
    // out = ret@Wout.T (fp32)
    gemm_nt_kernel<1, 0><<<dim3(DD/128, C/128, 1), b256, 0, stream>>>(cE, Woutb, nullptr, outf + c * C * DD, nullptr, nullptr, nullptr, 0.f, (int)DD, DD, 32);
  }
}